// Round 2
// baseline (332.360 us; speedup 1.0000x reference)
//
#include <hip/hip_runtime.h>

typedef unsigned short u16;
typedef unsigned int   u32;

typedef __bf16 bf16x8 __attribute__((ext_vector_type(8)));
typedef float  f32x4  __attribute__((ext_vector_type(4)));

__device__ __forceinline__ float bf2f(u16 v) {
    u32 u = ((u32)v) << 16; float f; __builtin_memcpy(&f, &u, 4); return f;
}
__device__ __forceinline__ u16 f2bf(float f) {
    u32 u; __builtin_memcpy(&u, &f, 4);
    u32 r = u + 0x7fffu + ((u >> 16) & 1u);
    return (u16)(r >> 16);
}

__device__ __forceinline__ void gload_lds16(const void* g, void* l) {
    __builtin_amdgcn_global_load_lds(
        (const __attribute__((address_space(1))) u32*)g,
        (__attribute__((address_space(3))) u32*)l, 16, 0, 0);
}

// ---------------------------------------------------------------------------
// f32 -> bf16 conversion (grid-stride, float4 loads)
// ---------------------------------------------------------------------------
__global__ __launch_bounds__(256) void cvt_kernel(
    const float* __restrict__ src, u16* __restrict__ dst, int n4)
{
    int i = blockIdx.x * blockDim.x + threadIdx.x;
    int stride = gridDim.x * blockDim.x;
    for (; i < n4; i += stride) {
        float4 v = reinterpret_cast<const float4*>(src)[i];
        ushort4 o;
        o.x = f2bf(v.x); o.y = f2bf(v.y); o.z = f2bf(v.z); o.w = f2bf(v.w);
        reinterpret_cast<ushort4*>(dst)[i] = o;
    }
}

// ---------------------------------------------------------------------------
// GEMM: C[M,N] = A[M,K] @ W[N,K]^T (+bias), bf16 in, f32 accum.
// Tile 128x128, BK=64, 4 waves (2x2), each wave 64x64 = 4x4 frags of 16x16x32.
// OUT_F32: write float (with f32 bias); else write bf16.
// ---------------------------------------------------------------------------
template<bool OUT_F32>
__global__ __launch_bounds__(256) void gemm_bt(
    const u16* __restrict__ A, const u16* __restrict__ W,
    const float* __restrict__ bias, void* __restrict__ Cv, int M)
{
    constexpr int Kd = 1024, Nd = 1024;
    __shared__ __align__(16) u16 As[128 * 64];
    __shared__ __align__(16) u16 Bs[128 * 64];

    const int tid = threadIdx.x;
    const int l = tid & 63, w = tid >> 6;
    const int brow = blockIdx.y * 128, bcol = blockIdx.x * 128;
    const int wr = (w >> 1) * 64, wc = (w & 1) * 64;
    const int fr = l & 15, fq = l >> 4;     // fragment row, k-group
    const int lr8 = l >> 3, lc8 = l & 7;    // staging lane decomposition

    f32x4 acc[4][4] = {};

    for (int k0 = 0; k0 < Kd; k0 += 64) {
        #pragma unroll
        for (int i = 0; i < 4; i++) {
            int c = w * 4 + i;  // chunk: 8 rows x 128B
            const u16* ga = A + (size_t)(brow + c * 8 + lr8) * Kd + k0 + lc8 * 8;
            gload_lds16(ga, &As[c * 512]);
            const u16* gb = W + (size_t)(bcol + c * 8 + lr8) * Kd + k0 + lc8 * 8;
            gload_lds16(gb, &Bs[c * 512]);
        }
        __syncthreads();

        #pragma unroll
        for (int kk = 0; kk < 2; kk++) {
            bf16x8 af[4], bfr[4];
            #pragma unroll
            for (int m = 0; m < 4; m++)
                af[m] = *reinterpret_cast<const bf16x8*>(
                    &As[(wr + m * 16 + fr) * 64 + kk * 32 + fq * 8]);
            #pragma unroll
            for (int n = 0; n < 4; n++)
                bfr[n] = *reinterpret_cast<const bf16x8*>(
                    &Bs[(wc + n * 16 + fr) * 64 + kk * 32 + fq * 8]);
            #pragma unroll
            for (int m = 0; m < 4; m++)
                #pragma unroll
                for (int n = 0; n < 4; n++)
                    acc[m][n] = __builtin_amdgcn_mfma_f32_16x16x32_bf16(
                        af[m], bfr[n], acc[m][n], 0, 0, 0);
        }
        __syncthreads();
    }

    // epilogue: D row = (lane>>4)*4 + reg, col = lane&15 (m89-verified)
    #pragma unroll
    for (int m = 0; m < 4; m++) {
        int row = brow + wr + m * 16 + fq * 4;
        #pragma unroll
        for (int n = 0; n < 4; n++) {
            int col = bcol + wc + n * 16 + fr;
            if (OUT_F32) {
                float bv = bias ? bias[col] : 0.0f;
                float* C = (float*)Cv;
                #pragma unroll
                for (int r = 0; r < 4; r++)
                    C[(size_t)(row + r) * Nd + col] = acc[m][n][r] + bv;
            } else {
                u16* C = (u16*)Cv;
                #pragma unroll
                for (int r = 0; r < 4; r++)
                    C[(size_t)(row + r) * Nd + col] = f2bf(acc[m][n][r]);
            }
        }
    }
}

// ---------------------------------------------------------------------------
// Flash attention with block-causal mask: allow iff (i>>1) >= j.
// Block: one (b,h), 64 q-rows; 4 waves x 16 rows. KV tiles of 64.
// ---------------------------------------------------------------------------
__global__ __launch_bounds__(256) void attn_kernel(
    const u16* __restrict__ Q, const u16* __restrict__ K,
    const u16* __restrict__ V, u16* __restrict__ O)
{
    __shared__ __align__(16) u16 Ks[64 * 64];     // [key][d]
    __shared__ __align__(16) u16 Vt[64 * 64];     // [d][key]
    __shared__ __align__(16) u16 Ps[4 * 16 * 64]; // per-wave P [16 q][64 key]

    const int tid = threadIdx.x;
    const int l = tid & 63, w = tid >> 6;
    const int bh = blockIdx.y, b = bh >> 4, h = bh & 15;
    const int q0 = blockIdx.x * 64;
    const int fr = l & 15, fq = l >> 4;

    bf16x8 qf[2];
    {
        size_t qoff = (size_t)(b * 2048 + q0 + w * 16 + fr) * 1024 + h * 64;
        qf[0] = *reinterpret_cast<const bf16x8*>(Q + qoff + fq * 8);
        qf[1] = *reinterpret_cast<const bf16x8*>(Q + qoff + 32 + fq * 8);
    }

    float m_old[4] = {-1e30f, -1e30f, -1e30f, -1e30f};
    float ssum[4] = {0.f, 0.f, 0.f, 0.f};
    f32x4 of[4] = {};

    const int ntiles = ((q0 + 63) >> 1) / 64 + 1;
    for (int t = 0; t < ntiles; ++t) {
        const int j0 = t * 64;
        #pragma unroll
        for (int i = 0; i < 2; i++) {
            int c = w * 2 + i;
            const u16* gk = K + (size_t)(b * 1024 + j0 + c * 8 + (l >> 3)) * 1024
                            + h * 64 + (l & 7) * 8;
            gload_lds16(gk, &Ks[c * 512]);
        }
        #pragma unroll
        for (int i = 0; i < 2; i++) {
            int c = tid + i * 256;            // 512 chunks of 8 elems
            int key = c >> 3, d0 = (c & 7) * 8;
            const u16* gv = V + (size_t)(b * 1024 + j0 + key) * 1024 + h * 64 + d0;
            uint4 pv = *reinterpret_cast<const uint4*>(gv);
            u16 e[8]; __builtin_memcpy(e, &pv, 16);
            #pragma unroll
            for (int jj = 0; jj < 8; jj++) Vt[(d0 + jj) * 64 + key] = e[jj];
        }
        __syncthreads();

        // S = Q K^T
        f32x4 sf[4] = {};
        #pragma unroll
        for (int kk = 0; kk < 2; kk++) {
            #pragma unroll
            for (int n = 0; n < 4; n++) {
                bf16x8 kf = *reinterpret_cast<const bf16x8*>(
                    &Ks[(n * 16 + fr) * 64 + kk * 32 + fq * 8]);
                sf[n] = __builtin_amdgcn_mfma_f32_16x16x32_bf16(qf[kk], kf, sf[n], 0, 0, 0);
            }
        }

        // mask + online softmax
        float p[4][4], rmax[4];
        #pragma unroll
        for (int r = 0; r < 4; r++) rmax[r] = -1e30f;
        #pragma unroll
        for (int n = 0; n < 4; n++) {
            int kg = j0 + n * 16 + fr;
            #pragma unroll
            for (int r = 0; r < 4; r++) {
                int qg = q0 + w * 16 + fq * 4 + r;
                float s = sf[n][r] * 0.125f;
                if ((qg >> 1) < kg) s = -1e30f;
                p[n][r] = s;
                rmax[r] = fmaxf(rmax[r], s);
            }
        }
        #pragma unroll
        for (int d = 1; d < 16; d <<= 1) {
            #pragma unroll
            for (int r = 0; r < 4; r++)
                rmax[r] = fmaxf(rmax[r], __shfl_xor(rmax[r], d));
        }
        float alpha[4], rsum[4];
        #pragma unroll
        for (int r = 0; r < 4; r++) {
            float mn = fmaxf(m_old[r], rmax[r]);
            alpha[r] = __expf(m_old[r] - mn);
            m_old[r] = mn;
            rsum[r] = 0.f;
        }
        #pragma unroll
        for (int n = 0; n < 4; n++)
            #pragma unroll
            for (int r = 0; r < 4; r++) {
                float e = __expf(p[n][r] - m_old[r]);
                p[n][r] = e;
                rsum[r] += e;
            }
        #pragma unroll
        for (int d = 1; d < 16; d <<= 1) {
            #pragma unroll
            for (int r = 0; r < 4; r++) rsum[r] += __shfl_xor(rsum[r], d);
        }
        #pragma unroll
        for (int r = 0; r < 4; r++) ssum[r] = ssum[r] * alpha[r] + rsum[r];
        #pragma unroll
        for (int n = 0; n < 4; n++)
            #pragma unroll
            for (int r = 0; r < 4; r++) of[n][r] *= alpha[r];

        // P -> LDS (per-wave region), C-layout write, A-layout read
        #pragma unroll
        for (int n = 0; n < 4; n++)
            #pragma unroll
            for (int r = 0; r < 4; r++)
                Ps[(w * 16 + fq * 4 + r) * 64 + n * 16 + fr] = f2bf(p[n][r]);

        // O += P V
        #pragma unroll
        for (int kk = 0; kk < 2; kk++) {
            bf16x8 pf = *reinterpret_cast<const bf16x8*>(
                &Ps[(w * 16 + fr) * 64 + kk * 32 + fq * 8]);
            #pragma unroll
            for (int n = 0; n < 4; n++) {
                bf16x8 vf = *reinterpret_cast<const bf16x8*>(
                    &Vt[(n * 16 + fr) * 64 + kk * 32 + fq * 8]);
                of[n] = __builtin_amdgcn_mfma_f32_16x16x32_bf16(pf, vf, of[n], 0, 0, 0);
            }
        }
        __syncthreads();
    }

    #pragma unroll
    for (int r = 0; r < 4; r++) {
        float inv = 1.0f / ssum[r];
        size_t row = (size_t)(b * 2048 + q0 + w * 16 + fq * 4 + r) * 1024 + h * 64;
        #pragma unroll
        for (int n = 0; n < 4; n++)
            O[row + n * 16 + fr] = f2bf(of[n][r] * inv);
    }
}

// ---------------------------------------------------------------------------
// LayerNorm in-place over rows of [8192][1024], bf16 data, f32 params/accum.
// ---------------------------------------------------------------------------
__global__ __launch_bounds__(256) void ln_kernel(
    u16* __restrict__ buf, const float* __restrict__ g, const float* __restrict__ beta)
{
    const int row = blockIdx.x, tid = threadIdx.x;
    const size_t base = (size_t)row * 1024;
    ushort4 v = *reinterpret_cast<const ushort4*>(&buf[base + tid * 4]);
    float x0 = bf2f(v.x), x1 = bf2f(v.y), x2 = bf2f(v.z), x3 = bf2f(v.w);
    float s = x0 + x1 + x2 + x3;
    float q = x0 * x0 + x1 * x1 + x2 * x2 + x3 * x3;
    #pragma unroll
    for (int d = 32; d; d >>= 1) { s += __shfl_xor(s, d); q += __shfl_xor(q, d); }
    __shared__ float sm[8];
    int w = tid >> 6, l = tid & 63;
    if (l == 0) { sm[w] = s; sm[4 + w] = q; }
    __syncthreads();
    s = sm[0] + sm[1] + sm[2] + sm[3];
    q = sm[4] + sm[5] + sm[6] + sm[7];
    float mean = s * (1.0f / 1024.0f);
    float var = q * (1.0f / 1024.0f) - mean * mean;
    float rstd = rsqrtf(var + 1e-5f);
    float4 gv = *reinterpret_cast<const float4*>(&g[tid * 4]);
    float4 bv = *reinterpret_cast<const float4*>(&beta[tid * 4]);
    ushort4 o;
    o.x = f2bf((x0 - mean) * rstd * gv.x + bv.x);
    o.y = f2bf((x1 - mean) * rstd * gv.y + bv.y);
    o.z = f2bf((x2 - mean) * rstd * gv.z + bv.z);
    o.w = f2bf((x3 - mean) * rstd * gv.w + bv.w);
    *reinterpret_cast<ushort4*>(&buf[base + tid * 4]) = o;
}

// ---------------------------------------------------------------------------
extern "C" void kernel_launch(void* const* d_in, const int* in_sizes, int n_in,
                              void* d_out, int out_size, void* d_ws, size_t ws_size,
                              hipStream_t stream)
{
    const float* q    = (const float*)d_in[0];
    const float* kv   = (const float*)d_in[1];
    const float* Wq   = (const float*)d_in[2];
    const float* Wk   = (const float*)d_in[3];
    const float* Wv   = (const float*)d_in[4];
    const float* Wo   = (const float*)d_in[5];
    const float* bo   = (const float*)d_in[6];
    const float* ln_g = (const float*)d_in[7];
    const float* ln_b = (const float*)d_in[8];

    const size_t MQ = (size_t)8192 * 1024;   // q rows x dim
    const size_t MK = (size_t)4096 * 1024;   // kv rows x dim
    const size_t MW = (size_t)1024 * 1024;

    u16* q8  = (u16*)d_ws;          // bf16 copies of inputs
    u16* kv8 = q8 + MQ;
    u16* Wq8 = kv8 + MK;
    u16* Wk8 = Wq8 + MW;
    u16* Wv8 = Wk8 + MW;
    u16* Wo8 = Wv8 + MW;
    u16* Qb  = Wo8 + MW;            // projections
    u16* Kb  = Qb + MQ;
    u16* Vb  = Kb + MK;
    u16* Ab  = Vb + MK;             // attn out (LN in-place)

    cvt_kernel<<<2048, 256, 0, stream>>>(q,  q8,  (int)(MQ / 4));
    cvt_kernel<<<2048, 256, 0, stream>>>(kv, kv8, (int)(MK / 4));
    cvt_kernel<<<1024, 256, 0, stream>>>(Wq, Wq8, (int)(MW / 4));
    cvt_kernel<<<1024, 256, 0, stream>>>(Wk, Wk8, (int)(MW / 4));
    cvt_kernel<<<1024, 256, 0, stream>>>(Wv, Wv8, (int)(MW / 4));
    cvt_kernel<<<1024, 256, 0, stream>>>(Wo, Wo8, (int)(MW / 4));

    gemm_bt<false><<<dim3(8, 64), 256, 0, stream>>>(q8,  Wq8, nullptr, Qb, 8192);
    gemm_bt<false><<<dim3(8, 32), 256, 0, stream>>>(kv8, Wk8, nullptr, Kb, 4096);
    gemm_bt<false><<<dim3(8, 32), 256, 0, stream>>>(kv8, Wv8, nullptr, Vb, 4096);
    attn_kernel<<<dim3(32, 64), 256, 0, stream>>>(Qb, Kb, Vb, Ab);
    ln_kernel<<<8192, 256, 0, stream>>>(Ab, ln_g, ln_b);
    gemm_bt<true><<<dim3(8, 64), 256, 0, stream>>>(Ab, Wo8, bo, d_out, 8192);
}

// Round 3
// 232.569 us; speedup vs baseline: 1.4291x; 1.4291x over previous
//
#include <hip/hip_runtime.h>

typedef unsigned short u16;
typedef unsigned int   u32;

typedef __bf16 bf16x8 __attribute__((ext_vector_type(8)));
typedef float  f32x4  __attribute__((ext_vector_type(4)));

__device__ __forceinline__ float bf2f(u16 v) {
    u32 u = ((u32)v) << 16; float f; __builtin_memcpy(&f, &u, 4); return f;
}
__device__ __forceinline__ u16 f2bf(float f) {
    u32 u; __builtin_memcpy(&u, &f, 4);
    u32 r = u + 0x7fffu + ((u >> 16) & 1u);
    return (u16)(r >> 16);
}

__device__ __forceinline__ void gload_lds16(const void* g, void* l) {
    __builtin_amdgcn_global_load_lds(
        (const __attribute__((address_space(1))) u32*)g,
        (__attribute__((address_space(3))) u32*)l, 16, 0, 0);
}

// ---------------------------------------------------------------------------
// f32 -> bf16 conversion (grid-stride, float4 loads)
// ---------------------------------------------------------------------------
__global__ __launch_bounds__(256) void cvt_kernel(
    const float* __restrict__ src, u16* __restrict__ dst, int n4)
{
    int i = blockIdx.x * blockDim.x + threadIdx.x;
    int stride = gridDim.x * blockDim.x;
    for (; i < n4; i += stride) {
        float4 v = reinterpret_cast<const float4*>(src)[i];
        ushort4 o;
        o.x = f2bf(v.x); o.y = f2bf(v.y); o.z = f2bf(v.z); o.w = f2bf(v.w);
        reinterpret_cast<ushort4*>(dst)[i] = o;
    }
}

// ---------------------------------------------------------------------------
// GEMM: C[M,N] = A[M,K] @ W[N,K]^T (+bias), bf16 in, f32 accum. (unchanged)
// ---------------------------------------------------------------------------
template<bool OUT_F32>
__global__ __launch_bounds__(256) void gemm_bt(
    const u16* __restrict__ A, const u16* __restrict__ W,
    const float* __restrict__ bias, void* __restrict__ Cv, int M)
{
    constexpr int Kd = 1024, Nd = 1024;
    __shared__ __align__(16) u16 As[128 * 64];
    __shared__ __align__(16) u16 Bs[128 * 64];

    const int tid = threadIdx.x;
    const int l = tid & 63, w = tid >> 6;
    const int brow = blockIdx.y * 128, bcol = blockIdx.x * 128;
    const int wr = (w >> 1) * 64, wc = (w & 1) * 64;
    const int fr = l & 15, fq = l >> 4;
    const int lr8 = l >> 3, lc8 = l & 7;

    f32x4 acc[4][4] = {};

    for (int k0 = 0; k0 < Kd; k0 += 64) {
        #pragma unroll
        for (int i = 0; i < 4; i++) {
            int c = w * 4 + i;
            const u16* ga = A + (size_t)(brow + c * 8 + lr8) * Kd + k0 + lc8 * 8;
            gload_lds16(ga, &As[c * 512]);
            const u16* gb = W + (size_t)(bcol + c * 8 + lr8) * Kd + k0 + lc8 * 8;
            gload_lds16(gb, &Bs[c * 512]);
        }
        __syncthreads();

        #pragma unroll
        for (int kk = 0; kk < 2; kk++) {
            bf16x8 af[4], bfr[4];
            #pragma unroll
            for (int m = 0; m < 4; m++)
                af[m] = *reinterpret_cast<const bf16x8*>(
                    &As[(wr + m * 16 + fr) * 64 + kk * 32 + fq * 8]);
            #pragma unroll
            for (int n = 0; n < 4; n++)
                bfr[n] = *reinterpret_cast<const bf16x8*>(
                    &Bs[(wc + n * 16 + fr) * 64 + kk * 32 + fq * 8]);
            #pragma unroll
            for (int m = 0; m < 4; m++)
                #pragma unroll
                for (int n = 0; n < 4; n++)
                    acc[m][n] = __builtin_amdgcn_mfma_f32_16x16x32_bf16(
                        af[m], bfr[n], acc[m][n], 0, 0, 0);
        }
        __syncthreads();
    }

    #pragma unroll
    for (int m = 0; m < 4; m++) {
        int row = brow + wr + m * 16 + fq * 4;
        #pragma unroll
        for (int n = 0; n < 4; n++) {
            int col = bcol + wc + n * 16 + fr;
            if (OUT_F32) {
                float bv = bias ? bias[col] : 0.0f;
                float* C = (float*)Cv;
                #pragma unroll
                for (int r = 0; r < 4; r++)
                    C[(size_t)(row + r) * Nd + col] = acc[m][n][r] + bv;
            } else {
                u16* C = (u16*)Cv;
                #pragma unroll
                for (int r = 0; r < 4; r++)
                    C[(size_t)(row + r) * Nd + col] = f2bf(acc[m][n][r]);
            }
        }
    }
}

// ---------------------------------------------------------------------------
// Flash attention, swapped-operand structure.
// Block: one (b,h), 128 q-rows; 4 waves x 32 q-rows. KV tiles of 64.
//   S^T = mfma(K, Q)      -> lane holds col q = lane&15, rows key = fq*4+r
//   O^T = mfma(V^T, P)    -> lane holds col q, rows d
// K LDS: [64 key][64 d] with 16B-group XOR swizzle (slot ^= row&7), staged by
//   global_load_lds with pre-swizzled per-lane SOURCE (LDS stays linear).
// V^T LDS: [64 d][64 key], same swizzle, built via paired-key u32 writes.
// P LDS: per-wave [32 q][72 u16] (pad to 144B rows), vector b64 writes.
// Block-causal mask: allow iff (i>>1) >= j; only diagonal tile masks.
// ---------------------------------------------------------------------------
__global__ __launch_bounds__(256) void attn_kernel(
    const u16* __restrict__ Q, const u16* __restrict__ K,
    const u16* __restrict__ V, u16* __restrict__ O)
{
    __shared__ __align__(16) u16 smem[17408];          // 34816 B
    u16* Ks = smem;                                    // 8192 B
    u16* Vt = smem + 4096;                             // 8192 B
    u16* Ps = smem + 8192;                             // 4 waves * 32 * 72 u16 = 18432 B
    float* Ow = (float*)smem;                          // overlay: 4 waves * 32 * 68 f32

    const int tid = threadIdx.x;
    const int l = tid & 63, w = tid >> 6;
    const int fr = l & 15, fq = l >> 4;
    const int bh = blockIdx.y, b = bh >> 4, h = bh & 15;
    const int bq = (int)gridDim.x - 1 - (int)blockIdx.x;  // heavy blocks first
    const int q0 = bq * 128;

    u16* Pw = Ps + w * (32 * 72);

    // Q fragments (B^T rows = Q rows, read once from global)
    bf16x8 qf[2][2];
    #pragma unroll
    for (int n = 0; n < 2; n++) {
        size_t qoff = (size_t)(b * 2048 + q0 + w * 32 + n * 16 + fr) * 1024 + h * 64;
        qf[n][0] = *reinterpret_cast<const bf16x8*>(Q + qoff + fq * 8);
        qf[n][1] = *reinterpret_cast<const bf16x8*>(Q + qoff + 32 + fq * 8);
    }

    float mx[2]   = {-1e30f, -1e30f};
    float ssum[2] = {0.f, 0.f};
    f32x4 of[4][2] = {};

    const int kp = tid & 31, d0 = (tid >> 5) * 8;  // V^T staging assignment

    for (int t = 0; t <= bq; ++t) {
        const int j0 = t * 64;

        // ---- stage K [64][64] swizzled, via global_load_lds ----
        #pragma unroll
        for (int i = 0; i < 2; i++) {
            int cI = w * 2 + i;
            int r = cI * 8 + (l >> 3), s = l & 7;
            const u16* src = K + (size_t)(b * 1024 + j0 + r) * 1024
                             + h * 64 + ((s ^ (r & 7)) * 8);
            gload_lds16(src, &Ks[cI * 512]);
        }
        // ---- stage V^T [64 d][64 key] swizzled, paired-key u32 writes ----
        {
            const u16* v0p = V + (size_t)(b * 1024 + j0 + 2 * kp) * 1024 + h * 64 + d0;
            uint4 ra = *reinterpret_cast<const uint4*>(v0p);
            uint4 rb = *reinterpret_cast<const uint4*>(v0p + 1024);
            u16 ea[8], eb[8];
            __builtin_memcpy(ea, &ra, 16);
            __builtin_memcpy(eb, &rb, 16);
            #pragma unroll
            for (int jd = 0; jd < 8; jd++) {
                int d = d0 + jd;
                u32 pk = (u32)ea[jd] | ((u32)eb[jd] << 16);
                *(u32*)((char*)Vt + d * 128 + (((kp >> 2) ^ (d & 7)) * 16)
                        + (kp & 3) * 4) = pk;
            }
        }
        __syncthreads();

        // ---- S^T = K * Q^T : 16 MFMA ----
        f32x4 sf[4][2] = {};
        #pragma unroll
        for (int kk = 0; kk < 2; kk++) {
            bf16x8 kf[4];
            #pragma unroll
            for (int m = 0; m < 4; m++) {
                int key = m * 16 + fr;
                kf[m] = *reinterpret_cast<const bf16x8*>(
                    (char*)Ks + key * 128 + (((kk * 4 + fq) ^ (key & 7)) * 16));
            }
            #pragma unroll
            for (int m = 0; m < 4; m++)
                #pragma unroll
                for (int n = 0; n < 2; n++)
                    sf[m][n] = __builtin_amdgcn_mfma_f32_16x16x32_bf16(
                        kf[m], qf[n][kk], sf[m][n], 0, 0, 0);
        }

        // ---- mask (diagonal tile only) + online softmax ----
        const bool diag = (t == bq);
        float tmax[2] = {-1e30f, -1e30f};
        #pragma unroll
        for (int m = 0; m < 4; m++)
            #pragma unroll
            for (int n = 0; n < 2; n++)
                #pragma unroll
                for (int r = 0; r < 4; r++) {
                    float s = sf[m][n][r] * 0.125f;
                    if (diag) {
                        int kl = m * 16 + fq * 4 + r;
                        int ql = w * 32 + n * 16 + fr;
                        if (kl > (ql >> 1)) s = -1e30f;
                    }
                    sf[m][n][r] = s;
                    tmax[n] = fmaxf(tmax[n], s);
                }
        #pragma unroll
        for (int n = 0; n < 2; n++) {
            tmax[n] = fmaxf(tmax[n], __shfl_xor(tmax[n], 16));
            tmax[n] = fmaxf(tmax[n], __shfl_xor(tmax[n], 32));
        }
        float al[2], rs[2];
        #pragma unroll
        for (int n = 0; n < 2; n++) {
            float mn = fmaxf(mx[n], tmax[n]);
            al[n] = __expf(mx[n] - mn);
            mx[n] = mn;
            rs[n] = 0.f;
        }
        #pragma unroll
        for (int m = 0; m < 4; m++)
            #pragma unroll
            for (int n = 0; n < 2; n++)
                #pragma unroll
                for (int r = 0; r < 4; r++) {
                    float e = __expf(sf[m][n][r] - mx[n]);
                    sf[m][n][r] = e;
                    rs[n] += e;
                }
        #pragma unroll
        for (int n = 0; n < 2; n++) {
            rs[n] += __shfl_xor(rs[n], 16);
            rs[n] += __shfl_xor(rs[n], 32);
            ssum[n] = ssum[n] * al[n] + rs[n];
        }
        #pragma unroll
        for (int m = 0; m < 4; m++)
            #pragma unroll
            for (int n = 0; n < 2; n++)
                of[m][n] *= al[n];

        // ---- P -> LDS [q][key], vector b64 writes (4 consecutive keys) ----
        #pragma unroll
        for (int m = 0; m < 4; m++)
            #pragma unroll
            for (int n = 0; n < 2; n++) {
                u32 lo = (u32)f2bf(sf[m][n][0]) | ((u32)f2bf(sf[m][n][1]) << 16);
                u32 hi = (u32)f2bf(sf[m][n][2]) | ((u32)f2bf(sf[m][n][3]) << 16);
                uint2 pk = make_uint2(lo, hi);
                int q = n * 16 + fr;
                *(uint2*)((char*)Pw + q * 144 + m * 32 + fq * 8) = pk;
            }

        // ---- O^T += V^T * P : 16 MFMA ----
        #pragma unroll
        for (int kk = 0; kk < 2; kk++) {
            bf16x8 pf[2], vf[4];
            #pragma unroll
            for (int n = 0; n < 2; n++) {
                int q = n * 16 + fr;
                pf[n] = *reinterpret_cast<const bf16x8*>(
                    (char*)Pw + q * 144 + kk * 64 + fq * 16);
            }
            #pragma unroll
            for (int m = 0; m < 4; m++) {
                int d = m * 16 + fr;
                vf[m] = *reinterpret_cast<const bf16x8*>(
                    (char*)Vt + d * 128 + (((kk * 4 + fq) ^ (d & 7)) * 16));
            }
            #pragma unroll
            for (int m = 0; m < 4; m++)
                #pragma unroll
                for (int n = 0; n < 2; n++)
                    of[m][n] = __builtin_amdgcn_mfma_f32_16x16x32_bf16(
                        vf[m], pf[n], of[m][n], 0, 0, 0);
        }
        __syncthreads();
    }

    // ---- epilogue: normalize, transpose O^T -> O via LDS, coalesced store ----
    float* OwW = Ow + w * (32 * 68);
    #pragma unroll
    for (int m = 0; m < 4; m++)
        #pragma unroll
        for (int n = 0; n < 2; n++) {
            f32x4 v = of[m][n] * (1.0f / ssum[n]);
            int q = n * 16 + fr;
            *reinterpret_cast<f32x4*>(&OwW[q * 68 + m * 16 + fq * 4]) = v;
        }
    // same-wave readback (no barrier needed)
    {
        int ql = l >> 1, dh = l & 1;
        size_t grow = (size_t)(b * 2048 + q0 + w * 32 + ql) * 1024 + h * 64 + dh * 32;
        #pragma unroll
        for (int p = 0; p < 4; p++) {
            f32x4 a = *reinterpret_cast<const f32x4*>(&OwW[ql * 68 + dh * 32 + p * 8]);
            f32x4 c = *reinterpret_cast<const f32x4*>(&OwW[ql * 68 + dh * 32 + p * 8 + 4]);
            u16 e[8];
            e[0]=f2bf(a[0]); e[1]=f2bf(a[1]); e[2]=f2bf(a[2]); e[3]=f2bf(a[3]);
            e[4]=f2bf(c[0]); e[5]=f2bf(c[1]); e[6]=f2bf(c[2]); e[7]=f2bf(c[3]);
            uint4 pk; __builtin_memcpy(&pk, e, 16);
            *reinterpret_cast<uint4*>(O + grow + p * 8) = pk;
        }
    }
}

// ---------------------------------------------------------------------------
// LayerNorm in-place over rows of [8192][1024], bf16 data, f32 params/accum.
// ---------------------------------------------------------------------------
__global__ __launch_bounds__(256) void ln_kernel(
    u16* __restrict__ buf, const float* __restrict__ g, const float* __restrict__ beta)
{
    const int row = blockIdx.x, tid = threadIdx.x;
    const size_t base = (size_t)row * 1024;
    ushort4 v = *reinterpret_cast<const ushort4*>(&buf[base + tid * 4]);
    float x0 = bf2f(v.x), x1 = bf2f(v.y), x2 = bf2f(v.z), x3 = bf2f(v.w);
    float s = x0 + x1 + x2 + x3;
    float q = x0 * x0 + x1 * x1 + x2 * x2 + x3 * x3;
    #pragma unroll
    for (int d = 32; d; d >>= 1) { s += __shfl_xor(s, d); q += __shfl_xor(q, d); }
    __shared__ float sm[8];
    int w = tid >> 6, l = tid & 63;
    if (l == 0) { sm[w] = s; sm[4 + w] = q; }
    __syncthreads();
    s = sm[0] + sm[1] + sm[2] + sm[3];
    q = sm[4] + sm[5] + sm[6] + sm[7];
    float mean = s * (1.0f / 1024.0f);
    float var = q * (1.0f / 1024.0f) - mean * mean;
    float rstd = rsqrtf(var + 1e-5f);
    float4 gv = *reinterpret_cast<const float4*>(&g[tid * 4]);
    float4 bv = *reinterpret_cast<const float4*>(&beta[tid * 4]);
    ushort4 o;
    o.x = f2bf((x0 - mean) * rstd * gv.x + bv.x);
    o.y = f2bf((x1 - mean) * rstd * gv.y + bv.y);
    o.z = f2bf((x2 - mean) * rstd * gv.z + bv.z);
    o.w = f2bf((x3 - mean) * rstd * gv.w + bv.w);
    *reinterpret_cast<ushort4*>(&buf[base + tid * 4]) = o;
}

// ---------------------------------------------------------------------------
extern "C" void kernel_launch(void* const* d_in, const int* in_sizes, int n_in,
                              void* d_out, int out_size, void* d_ws, size_t ws_size,
                              hipStream_t stream)
{
    const float* q    = (const float*)d_in[0];
    const float* kv   = (const float*)d_in[1];
    const float* Wq   = (const float*)d_in[2];
    const float* Wk   = (const float*)d_in[3];
    const float* Wv   = (const float*)d_in[4];
    const float* Wo   = (const float*)d_in[5];
    const float* bo   = (const float*)d_in[6];
    const float* ln_g = (const float*)d_in[7];
    const float* ln_b = (const float*)d_in[8];

    const size_t MQ = (size_t)8192 * 1024;
    const size_t MK = (size_t)4096 * 1024;
    const size_t MW = (size_t)1024 * 1024;

    u16* q8  = (u16*)d_ws;
    u16* kv8 = q8 + MQ;
    u16* Wq8 = kv8 + MK;
    u16* Wk8 = Wq8 + MW;
    u16* Wv8 = Wk8 + MW;
    u16* Wo8 = Wv8 + MW;
    u16* Qb  = Wo8 + MW;
    u16* Kb  = Qb + MQ;
    u16* Vb  = Kb + MK;
    u16* Ab  = Vb + MK;

    cvt_kernel<<<2048, 256, 0, stream>>>(q,  q8,  (int)(MQ / 4));
    cvt_kernel<<<2048, 256, 0, stream>>>(kv, kv8, (int)(MK / 4));
    cvt_kernel<<<1024, 256, 0, stream>>>(Wq, Wq8, (int)(MW / 4));
    cvt_kernel<<<1024, 256, 0, stream>>>(Wk, Wk8, (int)(MW / 4));
    cvt_kernel<<<1024, 256, 0, stream>>>(Wv, Wv8, (int)(MW / 4));
    cvt_kernel<<<1024, 256, 0, stream>>>(Wo, Wo8, (int)(MW / 4));

    gemm_bt<false><<<dim3(8, 64), 256, 0, stream>>>(q8,  Wq8, nullptr, Qb, 8192);
    gemm_bt<false><<<dim3(8, 32), 256, 0, stream>>>(kv8, Wk8, nullptr, Kb, 4096);
    gemm_bt<false><<<dim3(8, 32), 256, 0, stream>>>(kv8, Wv8, nullptr, Vb, 4096);
    attn_kernel<<<dim3(16, 64), 256, 0, stream>>>(Qb, Kb, Vb, Ab);
    ln_kernel<<<8192, 256, 0, stream>>>(Ab, ln_g, ln_b);
    gemm_bt<true><<<dim3(8, 64), 256, 0, stream>>>(Ab, Wo8, bo, (float*)d_out, 8192);
}

// Round 4
// 162.479 us; speedup vs baseline: 2.0456x; 1.4314x over previous
//
#include <hip/hip_runtime.h>

typedef unsigned short u16;
typedef unsigned int   u32;

typedef __bf16 bf16x8 __attribute__((ext_vector_type(8)));
typedef __bf16 bf16x4 __attribute__((ext_vector_type(4)));
typedef float  f32x4  __attribute__((ext_vector_type(4)));

__device__ __forceinline__ float bf2f(u16 v) {
    u32 u = ((u32)v) << 16; float f; __builtin_memcpy(&f, &u, 4); return f;
}
__device__ __forceinline__ u16 f2bf(float f) {
    __bf16 h = (__bf16)f; u16 r; __builtin_memcpy(&r, &h, 2); return r;
}

__device__ __forceinline__ void gload_lds16(const void* g, void* l) {
    __builtin_amdgcn_global_load_lds(
        (const __attribute__((address_space(1))) u32*)g,
        (__attribute__((address_space(3))) u32*)l, 16, 0, 0);
}

// ---------------------------------------------------------------------------
// f32 -> bf16 conversion (grid-stride, float4 loads)
// ---------------------------------------------------------------------------
__global__ __launch_bounds__(256) void cvt_kernel(
    const float* __restrict__ src, u16* __restrict__ dst, int n4)
{
    int i = blockIdx.x * blockDim.x + threadIdx.x;
    int stride = gridDim.x * blockDim.x;
    for (; i < n4; i += stride) {
        float4 v = reinterpret_cast<const float4*>(src)[i];
        ushort4 o;
        o.x = f2bf(v.x); o.y = f2bf(v.y); o.z = f2bf(v.z); o.w = f2bf(v.w);
        reinterpret_cast<ushort4*>(dst)[i] = o;
    }
}

// 4 same-size tensors in one launch (weights), blockIdx.y selects tensor
__global__ __launch_bounds__(256) void cvt4_kernel(
    const float* s0, const float* s1, const float* s2, const float* s3,
    u16* d0, u16* d1, u16* d2, u16* d3, int n4)
{
    const float* s = blockIdx.y == 0 ? s0 : blockIdx.y == 1 ? s1
                   : blockIdx.y == 2 ? s2 : s3;
    u16* d = blockIdx.y == 0 ? d0 : blockIdx.y == 1 ? d1
           : blockIdx.y == 2 ? d2 : d3;
    int i = blockIdx.x * blockDim.x + threadIdx.x;
    int stride = gridDim.x * blockDim.x;
    for (; i < n4; i += stride) {
        float4 v = reinterpret_cast<const float4*>(s)[i];
        ushort4 o;
        o.x = f2bf(v.x); o.y = f2bf(v.y); o.z = f2bf(v.z); o.w = f2bf(v.w);
        reinterpret_cast<ushort4*>(d)[i] = o;
    }
}

// ---------------------------------------------------------------------------
// GEMM core: C[*,N] = scale * (A[M,K] @ W[N,K]^T) (+bias), bf16 in, f32 accum.
// Tile 128x128, BK=64, 4 waves (2x2), 4x4 frags of 16x16x32 per wave.
// ---------------------------------------------------------------------------
template<bool OUT_F32>
__device__ __forceinline__ void gemm_core(
    const u16* __restrict__ A, const u16* __restrict__ W,
    const float* __restrict__ bias, void* __restrict__ Cv,
    float scale, int brow, int bcol)
{
    constexpr int Kd = 1024, Nd = 1024;
    __shared__ __align__(16) u16 As[128 * 64];
    __shared__ __align__(16) u16 Bs[128 * 64];

    const int tid = threadIdx.x;
    const int l = tid & 63, w = tid >> 6;
    const int wr = (w >> 1) * 64, wc = (w & 1) * 64;
    const int fr = l & 15, fq = l >> 4;
    const int lr8 = l >> 3, lc8 = l & 7;

    f32x4 acc[4][4] = {};

    for (int k0 = 0; k0 < Kd; k0 += 64) {
        #pragma unroll
        for (int i = 0; i < 4; i++) {
            int c = w * 4 + i;
            const u16* ga = A + (size_t)(brow + c * 8 + lr8) * Kd + k0 + lc8 * 8;
            gload_lds16(ga, &As[c * 512]);
            const u16* gb = W + (size_t)(bcol + c * 8 + lr8) * Kd + k0 + lc8 * 8;
            gload_lds16(gb, &Bs[c * 512]);
        }
        __syncthreads();

        #pragma unroll
        for (int kk = 0; kk < 2; kk++) {
            bf16x8 af[4], bfr[4];
            #pragma unroll
            for (int m = 0; m < 4; m++)
                af[m] = *reinterpret_cast<const bf16x8*>(
                    &As[(wr + m * 16 + fr) * 64 + kk * 32 + fq * 8]);
            #pragma unroll
            for (int n = 0; n < 4; n++)
                bfr[n] = *reinterpret_cast<const bf16x8*>(
                    &Bs[(wc + n * 16 + fr) * 64 + kk * 32 + fq * 8]);
            #pragma unroll
            for (int m = 0; m < 4; m++)
                #pragma unroll
                for (int n = 0; n < 4; n++)
                    acc[m][n] = __builtin_amdgcn_mfma_f32_16x16x32_bf16(
                        af[m], bfr[n], acc[m][n], 0, 0, 0);
        }
        __syncthreads();
    }

    #pragma unroll
    for (int m = 0; m < 4; m++) {
        int row = brow + wr + m * 16 + fq * 4;
        #pragma unroll
        for (int n = 0; n < 4; n++) {
            int col = bcol + wc + n * 16 + fr;
            if (OUT_F32) {
                float bv = bias ? bias[col] : 0.0f;
                float* C = (float*)Cv;
                #pragma unroll
                for (int r = 0; r < 4; r++)
                    C[(size_t)(row + r) * Nd + col] = acc[m][n][r] * scale + bv;
            } else {
                u16* C = (u16*)Cv;
                #pragma unroll
                for (int r = 0; r < 4; r++)
                    C[(size_t)(row + r) * Nd + col] = f2bf(acc[m][n][r] * scale);
            }
        }
    }
}

__global__ __launch_bounds__(256) void gemm_q(
    const u16* __restrict__ A, const u16* __restrict__ W, u16* __restrict__ C)
{
    gemm_core<false>(A, W, nullptr, C, 0.125f, blockIdx.y * 128, blockIdx.x * 128);
}

__global__ __launch_bounds__(256) void gemm_kv(
    const u16* __restrict__ A, const u16* __restrict__ Wk, const u16* __restrict__ Wv,
    u16* __restrict__ Kout, u16* __restrict__ Vout)
{
    const bool isV = blockIdx.x >= 8;
    gemm_core<false>(A, isV ? Wv : Wk, nullptr, isV ? (u16*)Vout : (u16*)Kout,
                     1.0f, blockIdx.y * 128, (blockIdx.x & 7) * 128);
}

__global__ __launch_bounds__(256) void gemm_out(
    const u16* __restrict__ A, const u16* __restrict__ W,
    const float* __restrict__ bias, float* __restrict__ C)
{
    gemm_core<true>(A, W, bias, C, 1.0f, blockIdx.y * 128, blockIdx.x * 128);
}

// ---------------------------------------------------------------------------
// Flash attention, swapped-operand, work-balanced, double-buffered staging.
// Grid: x=8 pairs, y=64 bh. Block handles q-chunks bq = 15-x (heavy) then x.
// Q pre-scaled by 1/8 in gemm_q.
//   S^T = mfma(K, Q), O^T = mfma(V^T, P); K/V^T swizzled; 2-phase pipeline.
// ---------------------------------------------------------------------------
__global__ __launch_bounds__(256) void attn_kernel(
    const u16* __restrict__ Q, const u16* __restrict__ K,
    const u16* __restrict__ V, u16* __restrict__ O)
{
    __shared__ __align__(16) u16 smem[25600];          // 51200 B
    u16* Ks = smem;                                    // [2][64*64]
    u16* Vt = smem + 8192;                             // [2][64*64]
    u16* Ps = smem + 16384;                            // 4 waves * 32 * 72
    float* Ow = (float*)smem;                          // epilogue overlay

    const int tid = threadIdx.x;
    const int l = tid & 63, w = tid >> 6;
    const int fr = l & 15, fq = l >> 4;
    const int bh = blockIdx.y, b = bh >> 4, h = bh & 15;
    const int kp = tid & 31, d0 = (tid >> 5) * 8;
    const int kr = l >> 3, ksw = l & 7;                // K staging decomposition
    u16* Pw = Ps + w * (32 * 72);

    const u16* Kbh = K + (size_t)b * 1024 * 1024 + h * 64;
    const u16* Vbh = V + (size_t)b * 1024 * 1024 + h * 64;

    for (int half = 0; half < 2; ++half) {
        const int bq = half ? (int)blockIdx.x : 15 - (int)blockIdx.x;
        const int q0 = bq * 128;

        if (half) __syncthreads();  // epilogue overlay -> staging reuse

        // Q fragments (pre-scaled by 0.125 in gemm_q)
        bf16x8 qf[2][2];
        #pragma unroll
        for (int n = 0; n < 2; n++) {
            size_t qoff = (size_t)(b * 2048 + q0 + w * 32 + n * 16 + fr) * 1024 + h * 64;
            qf[n][0] = *reinterpret_cast<const bf16x8*>(Q + qoff + fq * 8);
            qf[n][1] = *reinterpret_cast<const bf16x8*>(Q + qoff + 32 + fq * 8);
        }

        float mx[2]   = {-1e30f, -1e30f};
        float ssum[2] = {0.f, 0.f};
        f32x4 of[4][2] = {};

        // ---- prologue: stage tile 0 into buf 0 ----
        {
            #pragma unroll
            for (int i = 0; i < 2; i++) {
                int cI = w * 2 + i;
                int r = cI * 8 + kr;
                gload_lds16(Kbh + (size_t)r * 1024 + ((ksw ^ (r & 7)) * 8),
                            &Ks[cI * 512]);
            }
            const u16* vp = Vbh + (size_t)(2 * kp) * 1024 + d0;
            uint4 ra = *reinterpret_cast<const uint4*>(vp);
            uint4 rb = *reinterpret_cast<const uint4*>(vp + 1024);
            u16 ea[8], eb[8];
            __builtin_memcpy(ea, &ra, 16);
            __builtin_memcpy(eb, &rb, 16);
            #pragma unroll
            for (int jd = 0; jd < 8; jd++) {
                int d = d0 + jd;
                u32 pk = (u32)ea[jd] | ((u32)eb[jd] << 16);
                *(u32*)((char*)Vt + d * 128 + (((kp >> 2) ^ (d & 7)) * 16)
                        + (kp & 3) * 4) = pk;
            }
        }
        __syncthreads();

        int cur = 0;
        for (int t = 0; t <= bq; ++t) {
            const bool pre = (t < bq);
            uint4 ra, rb;
            // ---- issue next-tile staging (T3 2-phase) ----
            if (pre) {
                const int j0n = (t + 1) * 64;
                #pragma unroll
                for (int i = 0; i < 2; i++) {
                    int cI = w * 2 + i;
                    int r = cI * 8 + kr;
                    gload_lds16(Kbh + (size_t)(j0n + r) * 1024 + ((ksw ^ (r & 7)) * 8),
                                &Ks[(cur ^ 1) * 4096 + cI * 512]);
                }
                const u16* vp = Vbh + (size_t)(j0n + 2 * kp) * 1024 + d0;
                ra = *reinterpret_cast<const uint4*>(vp);
                rb = *reinterpret_cast<const uint4*>(vp + 1024);
            }

            // ---- S^T = K * Q^T ----
            f32x4 sf[4][2] = {};
            #pragma unroll
            for (int kk = 0; kk < 2; kk++) {
                bf16x8 kf[4];
                #pragma unroll
                for (int m = 0; m < 4; m++) {
                    int key = m * 16 + fr;
                    kf[m] = *reinterpret_cast<const bf16x8*>(
                        (char*)Ks + cur * 8192 + key * 128 + (((kk * 4 + fq) ^ (key & 7)) * 16));
                }
                #pragma unroll
                for (int m = 0; m < 4; m++)
                    #pragma unroll
                    for (int n = 0; n < 2; n++)
                        sf[m][n] = __builtin_amdgcn_mfma_f32_16x16x32_bf16(
                            kf[m], qf[n][kk], sf[m][n], 0, 0, 0);
            }

            // ---- mask (diag only) + online softmax ----
            const bool diag = (t == bq);
            float tmax[2] = {-1e30f, -1e30f};
            #pragma unroll
            for (int m = 0; m < 4; m++)
                #pragma unroll
                for (int n = 0; n < 2; n++)
                    #pragma unroll
                    for (int r = 0; r < 4; r++) {
                        float s = sf[m][n][r];
                        if (diag) {
                            int kl = m * 16 + fq * 4 + r;
                            int ql = w * 32 + n * 16 + fr;
                            if (kl > (ql >> 1)) s = -1e30f;
                        }
                        sf[m][n][r] = s;
                        tmax[n] = fmaxf(tmax[n], s);
                    }
            #pragma unroll
            for (int n = 0; n < 2; n++) {
                tmax[n] = fmaxf(tmax[n], __shfl_xor(tmax[n], 16));
                tmax[n] = fmaxf(tmax[n], __shfl_xor(tmax[n], 32));
            }
            float al[2], rs[2];
            #pragma unroll
            for (int n = 0; n < 2; n++) {
                float mn = fmaxf(mx[n], tmax[n]);
                al[n] = __expf(mx[n] - mn);
                mx[n] = mn;
                rs[n] = 0.f;
            }
            #pragma unroll
            for (int m = 0; m < 4; m++)
                #pragma unroll
                for (int n = 0; n < 2; n++)
                    #pragma unroll
                    for (int r = 0; r < 4; r++) {
                        float e = __expf(sf[m][n][r] - mx[n]);
                        sf[m][n][r] = e;
                        rs[n] += e;
                    }
            #pragma unroll
            for (int n = 0; n < 2; n++) {
                rs[n] += __shfl_xor(rs[n], 16);
                rs[n] += __shfl_xor(rs[n], 32);
                ssum[n] = ssum[n] * al[n] + rs[n];
            }
            #pragma unroll
            for (int m = 0; m < 4; m++)
                #pragma unroll
                for (int n = 0; n < 2; n++)
                    of[m][n] *= al[n];

            // ---- P -> per-wave LDS (vector writes, native cvt) ----
            #pragma unroll
            for (int m = 0; m < 4; m++)
                #pragma unroll
                for (int n = 0; n < 2; n++) {
                    bf16x4 pk;
                    pk[0] = (__bf16)sf[m][n][0]; pk[1] = (__bf16)sf[m][n][1];
                    pk[2] = (__bf16)sf[m][n][2]; pk[3] = (__bf16)sf[m][n][3];
                    int q = n * 16 + fr;
                    *(bf16x4*)((char*)Pw + q * 144 + m * 32 + fq * 8) = pk;
                }

            // ---- O^T += V^T * P ----
            #pragma unroll
            for (int kk = 0; kk < 2; kk++) {
                bf16x8 pf[2], vf[4];
                #pragma unroll
                for (int n = 0; n < 2; n++) {
                    int q = n * 16 + fr;
                    pf[n] = *reinterpret_cast<const bf16x8*>(
                        (char*)Pw + q * 144 + kk * 64 + fq * 16);
                }
                #pragma unroll
                for (int m = 0; m < 4; m++) {
                    int d = m * 16 + fr;
                    vf[m] = *reinterpret_cast<const bf16x8*>(
                        (char*)Vt + cur * 8192 + d * 128 + (((kk * 4 + fq) ^ (d & 7)) * 16));
                }
                #pragma unroll
                for (int m = 0; m < 4; m++)
                    #pragma unroll
                    for (int n = 0; n < 2; n++)
                        of[m][n] = __builtin_amdgcn_mfma_f32_16x16x32_bf16(
                            vf[m], pf[n], of[m][n], 0, 0, 0);
            }

            // ---- write next-tile V^T (loads have had compute to land) ----
            if (pre) {
                u16 ea[8], eb[8];
                __builtin_memcpy(ea, &ra, 16);
                __builtin_memcpy(eb, &rb, 16);
                #pragma unroll
                for (int jd = 0; jd < 8; jd++) {
                    int d = d0 + jd;
                    u32 pk = (u32)ea[jd] | ((u32)eb[jd] << 16);
                    *(u32*)((char*)Vt + (cur ^ 1) * 8192 + d * 128
                            + (((kp >> 2) ^ (d & 7)) * 16) + (kp & 3) * 4) = pk;
                }
            }
            __syncthreads();
            cur ^= 1;
        }

        // ---- epilogue: normalize, transpose via per-wave LDS, store ----
        float* OwW = Ow + w * (32 * 68);
        #pragma unroll
        for (int m = 0; m < 4; m++)
            #pragma unroll
            for (int n = 0; n < 2; n++) {
                f32x4 v = of[m][n] * (1.0f / ssum[n]);
                int q = n * 16 + fr;
                *reinterpret_cast<f32x4*>(&OwW[q * 68 + m * 16 + fq * 4]) = v;
            }
        {
            int ql = l >> 1, dh = l & 1;
            size_t grow = (size_t)(b * 2048 + q0 + w * 32 + ql) * 1024 + h * 64 + dh * 32;
            #pragma unroll
            for (int p = 0; p < 4; p++) {
                f32x4 a = *reinterpret_cast<const f32x4*>(&OwW[ql * 68 + dh * 32 + p * 8]);
                f32x4 c = *reinterpret_cast<const f32x4*>(&OwW[ql * 68 + dh * 32 + p * 8 + 4]);
                bf16x8 pk;
                pk[0]=(__bf16)a[0]; pk[1]=(__bf16)a[1]; pk[2]=(__bf16)a[2]; pk[3]=(__bf16)a[3];
                pk[4]=(__bf16)c[0]; pk[5]=(__bf16)c[1]; pk[6]=(__bf16)c[2]; pk[7]=(__bf16)c[3];
                *reinterpret_cast<bf16x8*>(O + grow + p * 8) = pk;
            }
        }
    }
}

// ---------------------------------------------------------------------------
// LayerNorm in-place over rows of [8192][1024], bf16 data, f32 params/accum.
// ---------------------------------------------------------------------------
__global__ __launch_bounds__(256) void ln_kernel(
    u16* __restrict__ buf, const float* __restrict__ g, const float* __restrict__ beta)
{
    const int row = blockIdx.x, tid = threadIdx.x;
    const size_t base = (size_t)row * 1024;
    ushort4 v = *reinterpret_cast<const ushort4*>(&buf[base + tid * 4]);
    float x0 = bf2f(v.x), x1 = bf2f(v.y), x2 = bf2f(v.z), x3 = bf2f(v.w);
    float s = x0 + x1 + x2 + x3;
    float q = x0 * x0 + x1 * x1 + x2 * x2 + x3 * x3;
    #pragma unroll
    for (int d = 32; d; d >>= 1) { s += __shfl_xor(s, d); q += __shfl_xor(q, d); }
    __shared__ float sm[8];
    int w = tid >> 6, l = tid & 63;
    if (l == 0) { sm[w] = s; sm[4 + w] = q; }
    __syncthreads();
    s = sm[0] + sm[1] + sm[2] + sm[3];
    q = sm[4] + sm[5] + sm[6] + sm[7];
    float mean = s * (1.0f / 1024.0f);
    float var = q * (1.0f / 1024.0f) - mean * mean;
    float rstd = rsqrtf(var + 1e-5f);
    float4 gv = *reinterpret_cast<const float4*>(&g[tid * 4]);
    float4 bv = *reinterpret_cast<const float4*>(&beta[tid * 4]);
    ushort4 o;
    o.x = f2bf((x0 - mean) * rstd * gv.x + bv.x);
    o.y = f2bf((x1 - mean) * rstd * gv.y + bv.y);
    o.z = f2bf((x2 - mean) * rstd * gv.z + bv.z);
    o.w = f2bf((x3 - mean) * rstd * gv.w + bv.w);
    *reinterpret_cast<ushort4*>(&buf[base + tid * 4]) = o;
}

// ---------------------------------------------------------------------------
extern "C" void kernel_launch(void* const* d_in, const int* in_sizes, int n_in,
                              void* d_out, int out_size, void* d_ws, size_t ws_size,
                              hipStream_t stream)
{
    const float* q    = (const float*)d_in[0];
    const float* kv   = (const float*)d_in[1];
    const float* Wq   = (const float*)d_in[2];
    const float* Wk   = (const float*)d_in[3];
    const float* Wv   = (const float*)d_in[4];
    const float* Wo   = (const float*)d_in[5];
    const float* bo   = (const float*)d_in[6];
    const float* ln_g = (const float*)d_in[7];
    const float* ln_b = (const float*)d_in[8];

    const size_t MQ = (size_t)8192 * 1024;
    const size_t MK = (size_t)4096 * 1024;
    const size_t MW = (size_t)1024 * 1024;

    u16* q8  = (u16*)d_ws;
    u16* kv8 = q8 + MQ;
    u16* Wq8 = kv8 + MK;
    u16* Wk8 = Wq8 + MW;
    u16* Wv8 = Wk8 + MW;
    u16* Wo8 = Wv8 + MW;
    u16* Qb  = Wo8 + MW;
    u16* Kb  = Qb + MQ;
    u16* Vb  = Kb + MK;
    u16* Ab  = Vb + MK;

    cvt_kernel<<<2048, 256, 0, stream>>>(q,  q8,  (int)(MQ / 4));
    cvt_kernel<<<2048, 256, 0, stream>>>(kv, kv8, (int)(MK / 4));
    cvt4_kernel<<<dim3(256, 4), 256, 0, stream>>>(Wq, Wk, Wv, Wo,
                                                  Wq8, Wk8, Wv8, Wo8, (int)(MW / 4));

    gemm_q  <<<dim3(8, 64), 256, 0, stream>>>(q8, Wq8, Qb);
    gemm_kv <<<dim3(16, 32), 256, 0, stream>>>(kv8, Wk8, Wv8, Kb, Vb);
    attn_kernel<<<dim3(8, 64), 256, 0, stream>>>(Qb, Kb, Vb, Ab);
    ln_kernel<<<8192, 256, 0, stream>>>(Ab, ln_g, ln_b);
    gemm_out<<<dim3(8, 64), 256, 0, stream>>>(Ab, Wo8, bo, (float*)d_out);
}